// Round 6
// baseline (108.775 us; speedup 1.0000x reference)
//
#include <hip/hip_runtime.h>
#include <math.h>

// DetectionLayer: x(32,255,76,76) f32 -> out(32,17328,85) f32
// Block (512 thr) = (b, row i, j-half jh). Output region of a block is
// CONTIGUOUS: 38 cols x 3 anchors x 85 attrs = 9690 floats (38.76KB).
// Phase A: read input coalesced (c-major, j fastest), apply the per-element
//          transform inline (sigmoid / exp*anc partials), write result into
//          an output-layout LDS buffer lds[j*255+c] (stride 255, 255%32=31
//          coprime -> conflict-free).
// Phase B: 114-unit corner fixup in LDS (each unit owns its 4 slots).
// Phase C: dump LDS -> global as float2 (contiguous, coalesced, conflict-free
//          b64 reads; 8B alignment holds for both halves).
// LDS 38.76KB -> 4 blocks/CU x 8 waves = 32 waves (100% theoretical occ).
// XCD swizzle: logical (b,i,jh), jh fastest; 4864%8==0 -> bijective.

#define NCH    255
#define NATTR  85
#define HW     5776
#define GW     76
#define NBATCH 32
#define BLOCK  512
#define JW     38                     // cols per block
#define NEL    (NCH * JW)             // 9690
#define NWG    (NBATCH * GW * 2)      // 4864
#define CHUNK  (NWG / 8)              // 608

__device__ __forceinline__ float sigm(float x) {
    return __builtin_amdgcn_rcpf(1.0f + __expf(-x));
}

__global__ __launch_bounds__(BLOCK) void det_kernel(const float* __restrict__ in,
                                                    float* __restrict__ out) {
    int hw = blockIdx.x;
    int L  = (hw & 7) * CHUNK + (hw >> 3);
    int jh = L & 1;
    int L2 = L >> 1;
    int i  = L2 % GW;
    int b  = L2 / GW;

    __shared__ float lds[NEL];

    const float* __restrict__ src =
        in + (size_t)b * (NCH * HW) + (size_t)i * GW + jh * JW;

    // ---- phase A: load + transform + scatter into output-layout LDS ----
    #pragma unroll 2
    for (int e = threadIdx.x; e < NEL; e += BLOCK) {
        int c = e / JW;               // channel 0..254
        int j = e - c * JW;           // local col 0..37
        float x = src[(size_t)c * HW + j];
        int a = (c * 771) >> 16;      // c/85 for c<255 (771 = ceil(2^16/85))
        int t = c - a * 85;
        float val;
        if ((unsigned)(t - 2) < 2u) { // t==2 || t==3: wh half-extent partial
            float anc = (t == 2)
                ? (((a == 0) ? 10.f : (a == 1) ? 16.f : 33.f) * (0.5f / 608.f))
                : (((a == 0) ? 13.f : (a == 1) ? 30.f : 23.f) * (0.5f / 608.f));
            val = __expf(x) * anc;
        } else {                      // sigmoid (t<2 partial, t>=4 final)
            val = sigm(x);
        }
        lds[j * NCH + c] = val;
    }
    __syncthreads();

    // ---- phase B: corner fixup (38 cols x 3 anchors, 4 slots each) ----
    if (threadIdx.x < JW * 3) {
        int j = threadIdx.x / 3;
        int a = threadIdx.x - 3 * j;
        float* p = &lds[j * NCH + a * NATTR];
        float s0 = p[0], s1 = p[1], w2 = p[2], h2 = p[3];
        float ix = (s0 * 1.05f - 0.025f + (float)(jh * JW + j)) * (1.0f / 76.0f);
        float iy = (s1 * 1.05f - 0.025f + (float)i) * (1.0f / 76.0f);
        p[0] = ix - w2;
        p[1] = iy - h2;
        p[2] = ix + w2;
        p[3] = iy + h2;
    }
    __syncthreads();

    // ---- phase C: contiguous float2 dump ----
    float2* __restrict__ dstv = (float2*)(out +
        ((size_t)b * 17328 + (size_t)i * 228) * NATTR + (size_t)jh * NEL);
    const float2* lv = (const float2*)lds;
    #pragma unroll 2
    for (int e = threadIdx.x; e < NEL / 2; e += BLOCK) {
        dstv[e] = lv[e];
    }
}

extern "C" void kernel_launch(void* const* d_in, const int* in_sizes, int n_in,
                              void* d_out, int out_size, void* d_ws, size_t ws_size,
                              hipStream_t stream) {
    const float* x = (const float*)d_in[0];
    float* out = (float*)d_out;
    det_kernel<<<NWG, BLOCK, 0, stream>>>(x, out);
}

// Round 7
// 84.466 us; speedup vs baseline: 1.2878x; 1.2878x over previous
//
#include <hip/hip_runtime.h>
#include <math.h>

// DetectionLayer: x(32,255,76,76) f32 -> out(32,17328,85) f32
// Block (1024 thr) = (b, row i). Register-carry hybrid:
//  Phase A : each thread loads the PAIR (c,j),(c,j+40) -> wave covers the
//            full 304B input row (best DRAM read geometry); transform inline
//            (one path per pair, same channel); j<40 half -> output-layout
//            LDS lds[j*255+c] (stride-1 lanes -> conflict-free); j>=40 half
//            -> 10 statically-indexed stash registers.
//  Fix A   : corner fixup for cols 0..39 (120 lanes).
//  Dump A  : contiguous float4 LDS->global (10200 floats, 16B-aligned).
//  Phase A2: stash regs -> LDS (cols 40..75 layout).
//  Fix B, Dump B (9180 floats).
// LDS 40800B (rounds to 40960) x 2 blocks/CU, 2x16 waves = 32 waves/CU.
// Writes per block: one dense contiguous 77.5KB region.
// XCD swizzle: logical (b,i) chunked; 2432%8==0 -> bijective.

#define NCH    255
#define NATTR  85
#define HW     5776
#define GW     76
#define NBATCH 32
#define BLOCK  1024
#define JA     40
#define JB     36
#define NELA   (NCH * JA)          // 10200
#define NELB   (NCH * JB)          // 9180
#define NITER  10                  // ceil(10200/1024)
#define NWG    (NBATCH * GW)       // 2432
#define CHUNK  (NWG / 8)           // 304

__device__ __forceinline__ float sigm(float x) {
    return __builtin_amdgcn_rcpf(1.0f + __expf(-x));
}

__global__ __launch_bounds__(BLOCK, 8) void det_kernel(const float* __restrict__ in,
                                                       float* __restrict__ out) {
    int hw = blockIdx.x;
    int L  = (hw & 7) * CHUNK + (hw >> 3);
    int i  = L % GW;
    int b  = L / GW;

    __shared__ float lds[NELA];    // 40800 B

    const float* __restrict__ src = in + (size_t)b * (NCH * HW) + (size_t)i * GW;
    float* __restrict__ dst = out + ((size_t)b * 17328 + (size_t)i * 228) * NATTR;
    const float fi = (float)i;

    float stash[NITER];

    // ---- phase A: paired full-row loads + transform ----
    #pragma unroll
    for (int k = 0; k < NITER; ++k) {
        int e = threadIdx.x + BLOCK * k;
        if (e < NELA) {
            int c  = e / JA;
            int jj = e - c * JA;
            const float* p = src + (size_t)c * HW + jj;
            float x0 = p[0];
            bool pair = (jj < JB);
            float x1 = pair ? p[JA] : 0.0f;
            int a = (c * 771) >> 16;        // c/85 (c<255)
            int t = c - 85 * a;
            float v0, v1;
            if ((unsigned)(t - 2) < 2u) {   // t==2||t==3: half-extent partial
                float anc = (t == 2)
                    ? (((a == 0) ? 10.f : (a == 1) ? 16.f : 33.f) * (0.5f / 608.f))
                    : (((a == 0) ? 13.f : (a == 1) ? 30.f : 23.f) * (0.5f / 608.f));
                v0 = __expf(x0) * anc;
                v1 = __expf(x1) * anc;
            } else {                        // sigmoid (t<2 partial, t>=4 final)
                v0 = sigm(x0);
                v1 = sigm(x1);
            }
            lds[jj * NCH + c] = v0;
            stash[k] = v1;
        }
    }
    __syncthreads();

    // ---- fixup A: corners for cols 0..39 ----
    if (threadIdx.x < JA * 3) {
        int j = threadIdx.x / 3;
        int a = threadIdx.x - 3 * j;
        float* p = &lds[j * NCH + a * NATTR];
        float s0 = p[0], s1 = p[1], w2 = p[2], h2 = p[3];
        float ix = (s0 * 1.05f - 0.025f + (float)j) * (1.0f / 76.0f);
        float iy = (s1 * 1.05f - 0.025f + fi) * (1.0f / 76.0f);
        p[0] = ix - w2; p[1] = iy - h2; p[2] = ix + w2; p[3] = iy + h2;
    }
    __syncthreads();

    // ---- dump A: 10200 floats = 2550 float4, contiguous ----
    {
        float4* __restrict__ dv = (float4*)dst;
        const float4* lv = (const float4*)lds;
        #pragma unroll
        for (int k = 0; k < 3; ++k) {
            int e = threadIdx.x + BLOCK * k;
            if (e < NELA / 4) dv[e] = lv[e];
        }
    }
    __syncthreads();

    // ---- phase A2: stash -> LDS (cols 40..75) ----
    #pragma unroll
    for (int k = 0; k < NITER; ++k) {
        int e = threadIdx.x + BLOCK * k;
        if (e < NELA) {
            int c  = e / JA;
            int jj = e - c * JA;
            if (jj < JB) lds[jj * NCH + c] = stash[k];
        }
    }
    __syncthreads();

    // ---- fixup B: corners for cols 40..75 ----
    if (threadIdx.x < JB * 3) {
        int j = threadIdx.x / 3;
        int a = threadIdx.x - 3 * j;
        float* p = &lds[j * NCH + a * NATTR];
        float s0 = p[0], s1 = p[1], w2 = p[2], h2 = p[3];
        float ix = (s0 * 1.05f - 0.025f + (float)(JA + j)) * (1.0f / 76.0f);
        float iy = (s1 * 1.05f - 0.025f + fi) * (1.0f / 76.0f);
        p[0] = ix - w2; p[1] = iy - h2; p[2] = ix + w2; p[3] = iy + h2;
    }
    __syncthreads();

    // ---- dump B: 9180 floats = 2295 float4, contiguous ----
    {
        float4* __restrict__ dv = (float4*)(dst + NELA);
        const float4* lv = (const float4*)lds;
        #pragma unroll
        for (int k = 0; k < 3; ++k) {
            int e = threadIdx.x + BLOCK * k;
            if (e < NELB / 4) dv[e] = lv[e];
        }
    }
}

extern "C" void kernel_launch(void* const* d_in, const int* in_sizes, int n_in,
                              void* d_out, int out_size, void* d_ws, size_t ws_size,
                              hipStream_t stream) {
    const float* x = (const float*)d_in[0];
    float* out = (float*)d_out;
    det_kernel<<<NWG, BLOCK, 0, stream>>>(x, out);
}

// Round 8
// 79.683 us; speedup vs baseline: 1.3651x; 1.0600x over previous
//
#include <hip/hip_runtime.h>
#include <math.h>

// DetectionLayer: x(32,255,76,76) f32 -> out(32,17328,85) f32
// Block (512 thr) = (b, row i, j-half). jh=0: cols [0,40), jh=1: cols [40,76).
// Phase A1: BATCHED loads -> x0[k],x1[k] register arrays (~20 in-flight
//           4B loads/thread; pair (jj, jj+HALF) shares one base address).
// Phase A2: transform (path uniform per channel) + output-layout LDS write
//           lds[jj*255+c] (lane stride 255 -> 255%32=31 coprime, conflict-free).
// Fixup   : 3*JW lanes finalize the 4 corner slots in LDS.
// Dump    : contiguous float4 LDS->global (regions 16B-aligned: 10200%4==0).
// LDS 40800B -> 4 blocks/CU x 8 waves = 32 waves/CU, 4 barrier domains.
// XCD swizzle: logical (b,i,jh), jh fastest; 4864%8==0 -> bijective.

#define NCH    255
#define NATTR  85
#define HW     5776
#define GW     76
#define NBATCH 32
#define BLOCK  512
#define NWG    (NBATCH * GW * 2)   // 4864
#define CHUNK  (NWG / 8)           // 608

__device__ __forceinline__ float sigm(float x) {
    return __builtin_amdgcn_rcpf(1.0f + __expf(-x));
}

template<int JW>   // 40 (jh=0) or 36 (jh=1)
__device__ __forceinline__ void run_half(const float* __restrict__ src,
                                         float* __restrict__ dst,
                                         float* __restrict__ lds,
                                         int i, int j0) {
    constexpr int HALF = JW / 2;                   // 20 / 18
    constexpr int NU   = NCH * HALF;               // 5100 / 4590
    constexpr int NIT  = (NU + BLOCK - 1) / BLOCK; // 10 / 9

    float x0[NIT], x1[NIT];

    // ---- phase A1: batched paired loads ----
    #pragma unroll
    for (int k = 0; k < NIT; ++k) {
        int e = threadIdx.x + BLOCK * k;
        if (e < NU) {
            int c  = e / HALF;
            int jj = e - c * HALF;
            const float* p = src + (size_t)c * HW + jj;
            x0[k] = p[0];
            x1[k] = p[HALF];
        }
    }

    // ---- phase A2: transform + LDS scatter (output layout) ----
    #pragma unroll
    for (int k = 0; k < NIT; ++k) {
        int e = threadIdx.x + BLOCK * k;
        if (e < NU) {
            int c  = e / HALF;
            int jj = e - c * HALF;
            int a  = (c * 771) >> 16;      // c/85 for c<255
            int t  = c - 85 * a;
            float v0, v1;
            if ((unsigned)(t - 2) < 2u) {  // t==2||t==3: half-extent partial
                float anc = (t == 2)
                    ? (((a == 0) ? 10.f : (a == 1) ? 16.f : 33.f) * (0.5f / 608.f))
                    : (((a == 0) ? 13.f : (a == 1) ? 30.f : 23.f) * (0.5f / 608.f));
                v0 = __expf(x0[k]) * anc;
                v1 = __expf(x1[k]) * anc;
            } else {                       // sigmoid (t<2 partial, t>=4 final)
                v0 = sigm(x0[k]);
                v1 = sigm(x1[k]);
            }
            lds[jj * NCH + c]          = v0;
            lds[(jj + HALF) * NCH + c] = v1;
        }
    }
    __syncthreads();

    // ---- fixup: corners (JW cols x 3 anchors, 4 slots each) ----
    if (threadIdx.x < JW * 3) {
        int j = threadIdx.x / 3;
        int a = threadIdx.x - 3 * j;
        float* p = &lds[j * NCH + a * NATTR];
        float s0 = p[0], s1 = p[1], w2 = p[2], h2 = p[3];
        float ix = (s0 * 1.05f - 0.025f + (float)(j0 + j)) * (1.0f / 76.0f);
        float iy = (s1 * 1.05f - 0.025f + (float)i) * (1.0f / 76.0f);
        p[0] = ix - w2; p[1] = iy - h2; p[2] = ix + w2; p[3] = iy + h2;
    }
    __syncthreads();

    // ---- dump: contiguous float4 ----
    constexpr int NV = (NCH * JW) / 4;   // 2550 / 2295
    float4* __restrict__ dv = (float4*)dst;
    const float4* lv = (const float4*)lds;
    #pragma unroll
    for (int k = 0; k < (NV + BLOCK - 1) / BLOCK; ++k) {
        int e = threadIdx.x + BLOCK * k;
        if (e < NV) dv[e] = lv[e];
    }
}

__global__ __launch_bounds__(BLOCK, 8) void det_kernel(const float* __restrict__ in,
                                                       float* __restrict__ out) {
    __shared__ float lds[NCH * 40];    // 40800 B

    int hw = blockIdx.x;
    int L  = (hw & 7) * CHUNK + (hw >> 3);
    int jh = L & 1;
    int L2 = L >> 1;
    int i  = L2 % GW;
    int b  = L2 / GW;

    const float* __restrict__ src = in + (size_t)b * (NCH * HW) + (size_t)i * GW;
    float* __restrict__ dst = out + ((size_t)b * 17328 + (size_t)i * 228) * NATTR;

    if (jh == 0) {
        run_half<40>(src, dst, lds, i, 0);
    } else {
        run_half<36>(src + 40, dst + NCH * 40, lds, i, 40);
    }
}

extern "C" void kernel_launch(void* const* d_in, const int* in_sizes, int n_in,
                              void* d_out, int out_size, void* d_ws, size_t ws_size,
                              hipStream_t stream) {
    const float* x = (const float*)d_in[0];
    float* out = (float*)d_out;
    det_kernel<<<NWG, BLOCK, 0, stream>>>(x, out);
}

// Round 9
// 78.547 us; speedup vs baseline: 1.3848x; 1.0145x over previous
//
#include <hip/hip_runtime.h>
#include <math.h>

// DetectionLayer: x(32,255,76,76) f32 -> out(32,17328,85) f32
// Block (512 thr) = (b, row i, j-half). jh=0: cols [0,40), jh=1: cols [40,76).
// Phase A: batched float4 loads (NQ=10|9 vec4/channel, 5 in flight/thread,
//          all 16B-aligned since 304B rows and 23104B channel stride are
//          16B multiples).
// Phase B: transform in registers. Corner channels (t<4, 12/255) load the
//          partner channel (c+-2, cache-warm) and produce FINAL corner values
//          inline -> no fixup phase, single barrier per block.
//          a = c/85 exact (NOTE: (c*771)>>16 is WRONG for c=85,170).
//          LDS write in output layout lds[j*255+c] (4 ds_writes per vec4).
// Phase C: contiguous float4 dump (10200 | 9180 floats, both 16B-aligned).
// LDS 40800B -> 4 blocks/CU x 8 waves = 32 waves/CU, 1 barrier per block.
// XCD swizzle: logical (b,i,jh), jh fastest; 4864%8==0 -> bijective.

#define NCH    255
#define NATTR  85
#define HW     5776
#define GW     76
#define NBATCH 32
#define BLOCK  512
#define NWG    (NBATCH * GW * 2)   // 4864
#define CHUNK  (NWG / 8)           // 608

__device__ __forceinline__ float sigm(float x) {
    return __builtin_amdgcn_rcpf(1.0f + __expf(-x));
}

template<int NQ>   // float4 units per channel: 10 (jh=0) or 9 (jh=1)
__device__ __forceinline__ void run_half(const float* __restrict__ src,
                                         float* __restrict__ dst,
                                         float* __restrict__ lds,
                                         int jg0, float fi) {
    constexpr int NU  = NCH * NQ;                  // 2550 / 2295 vec4 units
    constexpr int NIT = (NU + BLOCK - 1) / BLOCK;  // 5 / 5

    float4 xv[NIT];

    // ---- phase A: batched float4 loads ----
    #pragma unroll
    for (int k = 0; k < NIT; ++k) {
        int e = threadIdx.x + BLOCK * k;
        if (e < NU) {
            int c = e / NQ, q = e - c * NQ;
            xv[k] = *(const float4*)(src + (size_t)c * HW + 4 * q);
        }
    }

    // ---- phase B: transform + output-layout LDS write ----
    #pragma unroll
    for (int k = 0; k < NIT; ++k) {
        int e = threadIdx.x + BLOCK * k;
        if (e < NU) {
            int c = e / NQ, q = e - c * NQ;
            int a = c / 85;              // exact (compiler magic-mul)
            int t = c - 85 * a;
            float4 v = xv[k];
            float r0, r1, r2, r3;
            if (t >= 4) {
                r0 = sigm(v.x); r1 = sigm(v.y); r2 = sigm(v.z); r3 = sigm(v.w);
            } else {
                // final corner values inline; partner channel is cache-warm
                int cp = (t < 2) ? c + 2 : c - 2;
                float4 pv = *(const float4*)(src + (size_t)cp * HW + 4 * q);
                float ancw = (a == 0) ? 10.f : (a == 1) ? 16.f : 33.f;
                float anch = (a == 0) ? 13.f : (a == 1) ? 30.f : 23.f;
                float anc  = ((t & 1) ? anch : ancw) * (0.5f / 608.f);
                float vv[4] = {v.x, v.y, v.z, v.w};
                float pp[4] = {pv.x, pv.y, pv.z, pv.w};
                float rr[4];
                #pragma unroll
                for (int m = 0; m < 4; ++m) {
                    float coord = (t & 1) ? fi : (float)(jg0 + 4 * q + m);
                    float sin_ = (t < 2) ? vv[m] : pp[m];   // sigmoid input
                    float ein_ = (t < 2) ? pp[m] : vv[m];   // exp input
                    float ixy = (sigm(sin_) * 1.05f - 0.025f + coord) * (1.0f / 76.0f);
                    float wh2 = __expf(ein_) * anc;
                    rr[m] = (t < 2) ? (ixy - wh2) : (ixy + wh2);
                }
                r0 = rr[0]; r1 = rr[1]; r2 = rr[2]; r3 = rr[3];
            }
            float* lp = &lds[(4 * q) * NCH + c];
            lp[0]       = r0;
            lp[NCH]     = r1;
            lp[2 * NCH] = r2;
            lp[3 * NCH] = r3;
        }
    }
    __syncthreads();

    // ---- phase C: contiguous float4 dump ----
    float4* __restrict__ dv = (float4*)dst;
    const float4* lv = (const float4*)lds;
    #pragma unroll
    for (int k = 0; k < NIT; ++k) {
        int e = threadIdx.x + BLOCK * k;
        if (e < NU) dv[e] = lv[e];
    }
}

__global__ __launch_bounds__(BLOCK, 8) void det_kernel(const float* __restrict__ in,
                                                       float* __restrict__ out) {
    __shared__ float lds[NCH * 40];    // 40800 B -> 4 blocks/CU

    int hw = blockIdx.x;
    int L  = (hw & 7) * CHUNK + (hw >> 3);
    int jh = L & 1;
    int L2 = L >> 1;
    int i  = L2 % GW;
    int b  = L2 / GW;

    const float* __restrict__ src = in + (size_t)b * (NCH * HW) + (size_t)i * GW;
    float* __restrict__ dst = out + ((size_t)b * 17328 + (size_t)i * 228) * NATTR;
    const float fi = (float)i;

    if (jh == 0) {
        run_half<10>(src, dst, lds, 0, fi);
    } else {
        run_half<9>(src + 40, dst + 40 * NCH, lds, 40, fi);
    }
}

extern "C" void kernel_launch(void* const* d_in, const int* in_sizes, int n_in,
                              void* d_out, int out_size, void* d_ws, size_t ws_size,
                              hipStream_t stream) {
    const float* x = (const float*)d_in[0];
    float* out = (float*)d_out;
    det_kernel<<<NWG, BLOCK, 0, stream>>>(x, out);
}